// Round 9
// baseline (197.506 us; speedup 1.0000x reference)
//
#include <hip/hip_runtime.h>

// CASREL loss, B=32,S=512,H=1024,R=64 -> scalar fp32 loss.
// v10: K-split barrier-free stream. v9 proved barrier-free streaming hits
// 1.33+ TB/s but its col-split doubled A traffic (FETCH 38->72MB, twins on
// different XCDs + L3 flushed by harness fills). Fix: block = 64 rows x all
// 144 used cols; B resident one K-half at a time (Bsm[144][512] bf16 =144KB);
// 2 phases of {stage + 1 barrier + barrier-free 16-k-step stream}. Each ctx
// byte read ONCE device-wide. 3 barriers total. 4 waves/block, wave = 16 rows
// x 9 tiles (acc 36 VGPR). Same K order/f2bf/MFMA -> bit-identical numerics.
// aux_kernel unchanged (verified).

#define B_  32
#define S_  512
#define H_  1024
#define R_  64
#define M_  (B_ * S_)      // 16384 rows
#define NPAD 160           // WtG rows built by aux (144..159 unused here)
#define NVALID 130
#define NCOL 144           // staged/computed cols (9 tiles of 16)
#define MT 64              // rows per block
#define PHK 512            // K per phase
#define TBLK 20            // transpose blocks (5 n-tiles x 4 k-tiles)

typedef __attribute__((ext_vector_type(4))) float  floatx4;
typedef __attribute__((ext_vector_type(8))) short  short8;     // 8 bf16
typedef __attribute__((ext_vector_type(8))) unsigned short u16x8;

__device__ __forceinline__ unsigned short f2bf(float f) {
    unsigned int u = __float_as_uint(f);
    u = (u + 0x7FFFu + ((u >> 16) & 1u)) >> 16;   // RNE
    return (unsigned short)u;
}

__device__ __forceinline__ short8 cvt8(float4 a, float4 b) {
    union { unsigned short us[8]; short8 s8; } u;
    u.us[0] = f2bf(a.x); u.us[1] = f2bf(a.y); u.us[2] = f2bf(a.z); u.us[3] = f2bf(a.w);
    u.us[4] = f2bf(b.x); u.us[5] = f2bf(b.y); u.us[6] = f2bf(b.z); u.us[7] = f2bf(b.w);
    return u.s8;
}

__device__ __forceinline__ void gload16(const void* g, void* l) {
    __builtin_amdgcn_global_load_lds(
        (const __attribute__((address_space(1))) unsigned int*)g,
        (__attribute__((address_space(3))) unsigned int*)l, 16, 0, 0);
}

// ---- K1 (merged): blocks [0,TBLK) transpose WtG; blocks [TBLK,TBLK+B_) subj ----
__global__ __launch_bounds__(256) void aux_kernel(
        const float* __restrict__ ctx, const float* __restrict__ head,
        const float* __restrict__ tail, const float* __restrict__ masks,
        const float* __restrict__ Wo_h, const float* __restrict__ Wo_t,
        const float* __restrict__ Ws_h, const float* __restrict__ Ws_t,
        const float* __restrict__ bo_h, const float* __restrict__ bo_t,
        const float* __restrict__ bs_h, const float* __restrict__ bs_t,
        unsigned short* __restrict__ WtG, float* __restrict__ rowBias,
        float* __restrict__ accum) {
    const int tid = threadIdx.x;
    __shared__ float tr[32][257];      // transpose tile (pad 257: conflict-free)
    __shared__ float subj[H_];
    __shared__ float partS[4][256];
    __shared__ int cnt;
    __shared__ int   sidx[8];
    __shared__ float sw[8];

    if (blockIdx.x < TBLK) {
        const int kt = blockIdx.x / 5, nt = blockIdx.x % 5;
        const int k0 = kt * 256, n0 = nt * 32;
        if (n0 < 128) {
            const float* src = (n0 < 64) ? Wo_h : Wo_t;
            const int cb = n0 & 63;
            const int nn = tid & 31, kk = tid >> 5;   // 8 k-rows per pass
#pragma unroll
            for (int i = 0; i < 32; ++i) {
                const int k = k0 + i * 8 + kk;
                tr[nn][i * 8 + kk] = src[(size_t)k * R_ + cb + nn];
            }
            __syncthreads();
#pragma unroll
            for (int p = 0; p < 4; ++p) {
                const int chunk = p * 256 + tid;
                const int n = chunk >> 5;             // 0..31
                const int kc = (chunk & 31) * 8;
                u16x8 v;
#pragma unroll
                for (int j = 0; j < 8; ++j) v[j] = f2bf(tr[n][kc + j]);
                *(u16x8*)(WtG + (size_t)(n0 + n) * H_ + k0 + kc) = v;
            }
        } else {
#pragma unroll
            for (int p = 0; p < 4; ++p) {
                const int chunk = p * 256 + tid;
                const int n = 128 + (chunk >> 5);
                const int kc = (chunk & 31) * 8;
                u16x8 v;
#pragma unroll
                for (int j = 0; j < 8; ++j) {
                    float f = (n == 128) ? Ws_h[k0 + kc + j]
                            : (n == 129) ? Ws_t[k0 + kc + j] : 0.0f;
                    v[j] = f2bf(f);
                }
                *(u16x8*)(WtG + (size_t)n * H_ + k0 + kc) = v;
            }
        }
        return;
    }

    const int b = blockIdx.x - TBLK;
    if (tid == 0) cnt = 0;
    __syncthreads();
    float msk = 0.0f;
    for (int s = tid; s < S_; s += 256) {
        float w = 0.5f * (head[b * S_ + s] + tail[b * S_ + s]);
        if (w != 0.0f) {
            int i = atomicAdd(&cnt, 1);
            if (i < 8) { sidx[i] = s; sw[i] = w; }
        }
        msk += masks[b * S_ + s];
    }
    for (int o = 32; o > 0; o >>= 1) msk += __shfl_down(msk, o, 64);
    if ((tid & 63) == 0) atomicAdd(&accum[1], msk);
    __syncthreads();
    const int nnz = cnt < 8 ? cnt : 8;
    for (int h = tid; h < H_; h += 256) {
        float a = 0.0f;
        for (int i = 0; i < nnz; i++)
            a += sw[i] * ctx[((size_t)b * S_ + sidx[i]) * H_ + h];
        subj[h] = a;
    }
    __syncthreads();
    {   // rowBias dot: thread = (c-group of 4, k-slice of 128); float4 W loads
        const int cg = tid & 31;
        const int ks = tid >> 5;
        const int c4 = cg * 4;
        const float* W = (c4 < 64) ? Wo_h : Wo_t;
        const int cc = c4 & 63;
        const int kk0 = ks * 128;
        float ax = 0.f, ay = 0.f, az = 0.f, aw2 = 0.f;
#pragma unroll 4
        for (int k = kk0; k < kk0 + 128; ++k) {
            const float4 w = *(const float4*)(W + (size_t)k * R_ + cc);
            const float sv = subj[k];
            ax += sv * w.x; ay += sv * w.y; az += sv * w.z; aw2 += sv * w.w;
        }
        partS[0][tid] = ax; partS[1][tid] = ay;
        partS[2][tid] = az; partS[3][tid] = aw2;
    }
    __syncthreads();
    if (tid < NPAD) {
        float bias = tid < 64  ? bo_h[tid]
                   : tid < 128 ? bo_t[tid - 64]
                   : tid == 128 ? bs_h[0]
                   : tid == 129 ? bs_t[0] : 0.0f;
        float a2 = 0.0f;
        if (tid < 128) {
            const int g = tid >> 2, j = tid & 3;
#pragma unroll
            for (int s = 0; s < 8; ++s) a2 += partS[j][s * 32 + g];
        }
        rowBias[b * NPAD + tid] = bias + a2;
    }
}

// ---- K2: K-split barrier-free GEMM + BCE + reduce + finalize ----
__global__ __launch_bounds__(256, 1) void main_kernel(
        const float* __restrict__ ctx, const unsigned short* __restrict__ WtG,
        const float* __restrict__ rowBias, const float* __restrict__ masks,
        const float* __restrict__ ash, const float* __restrict__ ast,
        const float* __restrict__ oh, const float* __restrict__ ot,
        float* __restrict__ accum, float* __restrict__ out) {
    __shared__ __align__(16) unsigned short Bsm[NCOL * PHK];   // 147456 B

    const int tid  = threadIdx.x;
    const int gm0  = blockIdx.x * MT;
    const int b    = gm0 >> 9;
    const int wave = tid >> 6, lane = tid & 63;
    const int lr = lane & 15, q = lane >> 4;     // q in 0..3

    // stage: chunk i = p*256+tid -> LDS linear [row][bcol]; source XOR-swizzled
#define STAGE(kbase) do {                                                      \
        _Pragma("unroll")                                                      \
        for (int p = 0; p < (NCOL * PHK * 2 / 16) / 256; ++p) {   /* 36 */     \
            const int i = p * 256 + tid;                                       \
            const int row = i >> 6;                                            \
            const int bcol = (i & 63) << 4;                                    \
            const int sb = bcol ^ ((row & 7) << 4);                            \
            gload16((const char*)(WtG + (size_t)row * H_ + (kbase)) + sb,      \
                    (char*)Bsm + (size_t)i * 16);                              \
        }                                                                      \
    } while (0)

    // compute-side maps
    const float* aP = ctx + (size_t)(gm0 + wave * 16 + lr) * H_ + q * 8;
    const int swzr = (lr & 7) << 4;
    int rb9[9];
#pragma unroll
    for (int t = 0; t < 9; ++t) rb9[t] = (t * 16 + lr) * 1024;   // bytes

    floatx4 acc[9];
#pragma unroll
    for (int t = 0; t < 9; ++t) acc[t] = (floatx4){0.f, 0.f, 0.f, 0.f};

#define COMPUTE(kbase) do {                                                    \
        _Pragma("unroll")                                                      \
        for (int ks = 0; ks < PHK / 32; ++ks) {            /* 16 k-steps */    \
            const float4 f0 = *(const float4*)(aP + (kbase) + ks * 32);        \
            const float4 f1 = *(const float4*)(aP + (kbase) + ks * 32 + 4);    \
            const short8 afr = cvt8(f0, f1);                                   \
            const int kb = (ks * 64 + q * 16) ^ swzr;                          \
            _Pragma("unroll")                                                  \
            for (int t = 0; t < 9; ++t) {                                      \
                const short8 bfr = *(const short8*)((const char*)Bsm + rb9[t] + kb);\
                acc[t] = __builtin_amdgcn_mfma_f32_16x16x32_bf16(afr, bfr, acc[t], 0, 0, 0);\
            }                                                                  \
        }                                                                      \
    } while (0)

    STAGE(0);
    __syncthreads();        // B half 0 resident
    COMPUTE(0);             // barrier-free stream, K 0..511
    __syncthreads();        // all reads of Bsm done
    STAGE(PHK);
    __syncthreads();        // B half 1 resident
    COMPUTE(PHK);           // barrier-free stream, K 512..1023
#undef STAGE
#undef COMPUTE

    // epilogue: logits -> BCE * mask -> per-wave sum -> atomic
    float lsum = 0.0f;
#pragma unroll
    for (int t = 0; t < 9; ++t) {
        const int col = t * 16 + lr;
        if (col < NVALID) {
            const float rbv = rowBias[b * NPAD + col];
#pragma unroll
            for (int i = 0; i < 4; ++i) {
                const int row = gm0 + wave * 16 + q * 4 + i;
                const float l = acc[t][i] + rbv;
                float tgt;
                if (col < 64)        tgt = oh[(size_t)row * R_ + col];
                else if (col < 128)  tgt = ot[(size_t)row * R_ + (col - 64)];
                else if (col == 128) tgt = ash[row];
                else                 tgt = ast[row];
                const float mk = masks[row];
                const float bce = fmaxf(l, 0.0f) - l * tgt + log1pf(__expf(-fabsf(l)));
                lsum += bce * mk;
            }
        }
    }
    for (int o = 32; o > 0; o >>= 1) lsum += __shfl_down(lsum, o, 64);
    if (lane == 0) {
        atomicAdd(&accum[0], lsum);          // one atomic per wave
        __threadfence();
        const unsigned int prev = atomicAdd((unsigned int*)(accum + 2), 1u);
        if (prev == 4u * gridDim.x - 1u) {   // last wave finalizes
            const float s = atomicAdd(&accum[0], 0.0f);
            const float m = atomicAdd(&accum[1], 0.0f);
            out[0] = s / m;
        }
    }
}

extern "C" void kernel_launch(void* const* d_in, const int* in_sizes, int n_in,
                              void* d_out, int out_size, void* d_ws, size_t ws_size,
                              hipStream_t stream) {
    const float* ctx   = (const float*)d_in[0];
    const float* masks = (const float*)d_in[1];
    const float* ash   = (const float*)d_in[2];
    const float* ast   = (const float*)d_in[3];
    const float* sh    = (const float*)d_in[4];
    const float* st    = (const float*)d_in[5];
    const float* oh    = (const float*)d_in[6];
    const float* ot    = (const float*)d_in[7];
    const float* Ws_h  = (const float*)d_in[8];
    const float* bs_h  = (const float*)d_in[9];
    const float* Ws_t  = (const float*)d_in[10];
    const float* bs_t  = (const float*)d_in[11];
    const float* Wo_h  = (const float*)d_in[12];
    const float* bo_h  = (const float*)d_in[13];
    const float* Wo_t  = (const float*)d_in[14];
    const float* bo_t  = (const float*)d_in[15];
    float* out = (float*)d_out;

    char* ws = (char*)d_ws;
    float* accum   = (float*)(ws + 0);                 // [0]=loss, [1]=msum, [2]=counter
    float* rowBias = (float*)(ws + 256);               // [32][160] fp32
    unsigned short* WtG = (unsigned short*)(ws + 256 + 32 * NPAD * 4); // [160][1024] bf16

    hipMemsetAsync(accum, 0, 12, stream);
    aux_kernel<<<TBLK + B_, 256, 0, stream>>>(ctx, sh, st, masks, Wo_h, Wo_t,
                                              Ws_h, Ws_t, bo_h, bo_t, bs_h, bs_t,
                                              WtG, rowBias, accum);
    main_kernel<<<M_ / MT, 256, 0, stream>>>(ctx, WtG, rowBias, masks,
                                             ash, ast, oh, ot, accum, out);
}

// Round 10
// 178.697 us; speedup vs baseline: 1.1053x; 1.1053x over previous
//
#include <hip/hip_runtime.h>

// CASREL loss, B=32,S=512,H=1024,R=64 -> scalar fp32 loss.
// v11: 16-wave K-split stream. Model (fits v1-v10): LDS-lockstep designs cap
// at ~950 GB/s (vmcnt drain in __syncthreads); direct-A streams scale with
// waves/CU at ~0.6 B/cy/wave (v9: 8w=1.33TB/s, v10: 4w=0.51TB/s). v10's 4-
// wave cap came from wave=16rows x all cols (M/16=1024 waves). Fix: split K
// across waves. Block = 64 rows x 144 cols, 16 waves = 4 row-groups x 4
// K-slices, grid 256 = 1 block/CU = 16 streaming waves/CU. B resident per
// K-half (Bsm[144][512]=144KB, verified XOR-involution DMA). A read directly
// from global (once device-wide). 5 barriers total. K-partials reduced via
// freed Bsm; BCE on kq=0 waves. aux_kernel unchanged (verified).

#define B_  32
#define S_  512
#define H_  1024
#define R_  64
#define M_  (B_ * S_)      // 16384 rows
#define NPAD 160
#define NVALID 130
#define NCOL 144           // 9 tiles of 16
#define MT 64              // rows per block
#define PHK 512            // K per phase
#define TBLK 20
#define NTHR 1024          // 16 waves

typedef __attribute__((ext_vector_type(4))) float  floatx4;
typedef __attribute__((ext_vector_type(8))) short  short8;     // 8 bf16
typedef __attribute__((ext_vector_type(8))) unsigned short u16x8;

__device__ __forceinline__ unsigned short f2bf(float f) {
    unsigned int u = __float_as_uint(f);
    u = (u + 0x7FFFu + ((u >> 16) & 1u)) >> 16;   // RNE
    return (unsigned short)u;
}

__device__ __forceinline__ short8 cvt8(float4 a, float4 b) {
    union { unsigned short us[8]; short8 s8; } u;
    u.us[0] = f2bf(a.x); u.us[1] = f2bf(a.y); u.us[2] = f2bf(a.z); u.us[3] = f2bf(a.w);
    u.us[4] = f2bf(b.x); u.us[5] = f2bf(b.y); u.us[6] = f2bf(b.z); u.us[7] = f2bf(b.w);
    return u.s8;
}

__device__ __forceinline__ void gload16(const void* g, void* l) {
    __builtin_amdgcn_global_load_lds(
        (const __attribute__((address_space(1))) unsigned int*)g,
        (__attribute__((address_space(3))) unsigned int*)l, 16, 0, 0);
}

// ---- K1 (merged): blocks [0,TBLK) transpose WtG; blocks [TBLK,TBLK+B_) subj ----
__global__ __launch_bounds__(256) void aux_kernel(
        const float* __restrict__ ctx, const float* __restrict__ head,
        const float* __restrict__ tail, const float* __restrict__ masks,
        const float* __restrict__ Wo_h, const float* __restrict__ Wo_t,
        const float* __restrict__ Ws_h, const float* __restrict__ Ws_t,
        const float* __restrict__ bo_h, const float* __restrict__ bo_t,
        const float* __restrict__ bs_h, const float* __restrict__ bs_t,
        unsigned short* __restrict__ WtG, float* __restrict__ rowBias,
        float* __restrict__ accum) {
    const int tid = threadIdx.x;
    __shared__ float tr[32][257];
    __shared__ float subj[H_];
    __shared__ float partS[4][256];
    __shared__ int cnt;
    __shared__ int   sidx[8];
    __shared__ float sw[8];

    if (blockIdx.x < TBLK) {
        const int kt = blockIdx.x / 5, nt = blockIdx.x % 5;
        const int k0 = kt * 256, n0 = nt * 32;
        if (n0 < 128) {
            const float* src = (n0 < 64) ? Wo_h : Wo_t;
            const int cb = n0 & 63;
            const int nn = tid & 31, kk = tid >> 5;
#pragma unroll
            for (int i = 0; i < 32; ++i) {
                const int k = k0 + i * 8 + kk;
                tr[nn][i * 8 + kk] = src[(size_t)k * R_ + cb + nn];
            }
            __syncthreads();
#pragma unroll
            for (int p = 0; p < 4; ++p) {
                const int chunk = p * 256 + tid;
                const int n = chunk >> 5;
                const int kc = (chunk & 31) * 8;
                u16x8 v;
#pragma unroll
                for (int j = 0; j < 8; ++j) v[j] = f2bf(tr[n][kc + j]);
                *(u16x8*)(WtG + (size_t)(n0 + n) * H_ + k0 + kc) = v;
            }
        } else {
#pragma unroll
            for (int p = 0; p < 4; ++p) {
                const int chunk = p * 256 + tid;
                const int n = 128 + (chunk >> 5);
                const int kc = (chunk & 31) * 8;
                u16x8 v;
#pragma unroll
                for (int j = 0; j < 8; ++j) {
                    float f = (n == 128) ? Ws_h[k0 + kc + j]
                            : (n == 129) ? Ws_t[k0 + kc + j] : 0.0f;
                    v[j] = f2bf(f);
                }
                *(u16x8*)(WtG + (size_t)n * H_ + k0 + kc) = v;
            }
        }
        return;
    }

    const int b = blockIdx.x - TBLK;
    if (tid == 0) cnt = 0;
    __syncthreads();
    float msk = 0.0f;
    for (int s = tid; s < S_; s += 256) {
        float w = 0.5f * (head[b * S_ + s] + tail[b * S_ + s]);
        if (w != 0.0f) {
            int i = atomicAdd(&cnt, 1);
            if (i < 8) { sidx[i] = s; sw[i] = w; }
        }
        msk += masks[b * S_ + s];
    }
    for (int o = 32; o > 0; o >>= 1) msk += __shfl_down(msk, o, 64);
    if ((tid & 63) == 0) atomicAdd(&accum[1], msk);
    __syncthreads();
    const int nnz = cnt < 8 ? cnt : 8;
    for (int h = tid; h < H_; h += 256) {
        float a = 0.0f;
        for (int i = 0; i < nnz; i++)
            a += sw[i] * ctx[((size_t)b * S_ + sidx[i]) * H_ + h];
        subj[h] = a;
    }
    __syncthreads();
    {
        const int cg = tid & 31;
        const int ks = tid >> 5;
        const int c4 = cg * 4;
        const float* W = (c4 < 64) ? Wo_h : Wo_t;
        const int cc = c4 & 63;
        const int kk0 = ks * 128;
        float ax = 0.f, ay = 0.f, az = 0.f, aw2 = 0.f;
#pragma unroll 4
        for (int k = kk0; k < kk0 + 128; ++k) {
            const float4 w = *(const float4*)(W + (size_t)k * R_ + cc);
            const float sv = subj[k];
            ax += sv * w.x; ay += sv * w.y; az += sv * w.z; aw2 += sv * w.w;
        }
        partS[0][tid] = ax; partS[1][tid] = ay;
        partS[2][tid] = az; partS[3][tid] = aw2;
    }
    __syncthreads();
    if (tid < NPAD) {
        float bias = tid < 64  ? bo_h[tid]
                   : tid < 128 ? bo_t[tid - 64]
                   : tid == 128 ? bs_h[0]
                   : tid == 129 ? bs_t[0] : 0.0f;
        float a2 = 0.0f;
        if (tid < 128) {
            const int g = tid >> 2, j = tid & 3;
#pragma unroll
            for (int s = 0; s < 8; ++s) a2 += partS[j][s * 32 + g];
        }
        rowBias[b * NPAD + tid] = bias + a2;
    }
}

// ---- K2: 16-wave K-split streaming GEMM + BCE + reduce + finalize ----
__global__ __launch_bounds__(NTHR, 4) void main_kernel(
        const float* __restrict__ ctx, const unsigned short* __restrict__ WtG,
        const float* __restrict__ rowBias, const float* __restrict__ masks,
        const float* __restrict__ ash, const float* __restrict__ ast,
        const float* __restrict__ oh, const float* __restrict__ ot,
        float* __restrict__ accum, float* __restrict__ out) {
    __shared__ __align__(16) unsigned short Bsm[NCOL * PHK];   // 147456 B

    const int tid  = threadIdx.x;
    const int gm0  = blockIdx.x * MT;
    const int b    = gm0 >> 9;
    const int wave = tid >> 6, lane = tid & 63;
    const int rg = wave & 3;          // row group (16 rows)
    const int kq = wave >> 2;         // K quarter within phase (128 k)
    const int lr = lane & 15, q = lane >> 4;   // q in 0..3

    // ---- stage map: 9216 16B-chunks, 9 passes; linear LDS, XOR-swz source ----
#define STAGE(kbase) do {                                                      \
        _Pragma("unroll")                                                      \
        for (int p = 0; p < 9; ++p) {                                          \
            const int i = p * NTHR + tid;                                      \
            const int row = i >> 6;            /* 64 chunks per 512-k row */   \
            const int bcol = (i & 63) << 4;                                    \
            const int sb = bcol ^ ((row & 7) << 4);                            \
            gload16((const char*)(WtG + (size_t)row * H_ + (kbase)) + sb,      \
                    (char*)Bsm + (size_t)i * 16);                              \
        }                                                                      \
    } while (0)

    // ---- compute-side maps ----
    const float* aP = ctx + (size_t)(gm0 + rg * 16 + lr) * H_ + q * 8;
    const int swz = (lr & 7) << 4;
    int rb9[9];
#pragma unroll
    for (int t = 0; t < 9; ++t) rb9[t] = (t * 16 + lr) * 1024;   // bytes (row=1024B)

    floatx4 acc[9];
#pragma unroll
    for (int t = 0; t < 9; ++t) acc[t] = (floatx4){0.f, 0.f, 0.f, 0.f};

    // wave's K-slice within a phase: [kq*128, kq*128+128) -> 4 k-steps of 32
#define COMPUTE(kbase) do {                                                    \
        _Pragma("unroll")                                                      \
        for (int ks = 0; ks < 4; ++ks) {                                       \
            const int kl = kq * 128 + ks * 32;                                 \
            const float4 f0 = *(const float4*)(aP + (kbase) + kl);             \
            const float4 f1 = *(const float4*)(aP + (kbase) + kl + 4);         \
            const short8 afr = cvt8(f0, f1);                                   \
            const int kb = (kl * 2 + q * 16) ^ swz;                            \
            _Pragma("unroll")                                                  \
            for (int t = 0; t < 9; ++t) {                                      \
                const short8 bfr = *(const short8*)((const char*)Bsm + rb9[t] + kb);\
                acc[t] = __builtin_amdgcn_mfma_f32_16x16x32_bf16(afr, bfr, acc[t], 0, 0, 0);\
            }                                                                  \
        }                                                                      \
    } while (0)

    STAGE(0);
    __syncthreads();        // B half 0 resident
    COMPUTE(0);
    __syncthreads();        // reads done
    STAGE(PHK);
    __syncthreads();        // B half 1 resident
    COMPUTE(PHK);
    __syncthreads();        // reads done -> Bsm reusable as reduce scratch
#undef STAGE
#undef COMPUTE

    // ---- reduce K-quarters via LDS (12 slots x 2304 floats = 110KB) ----
    float* Rf = (float*)Bsm;
    if (kq > 0) {
        const int base = ((kq - 1) * 4 + rg) * 2304;
#pragma unroll
        for (int t = 0; t < 9; ++t)
#pragma unroll
            for (int i = 0; i < 4; ++i)
                Rf[base + (t * 4 + i) * 64 + lane] = acc[t][i];
    }
    __syncthreads();
    if (kq == 0) {
#pragma unroll
        for (int t = 0; t < 9; ++t)
#pragma unroll
            for (int i = 0; i < 4; ++i) {
                const int o = (t * 4 + i) * 64 + lane;
                acc[t][i] = ((acc[t][i] + Rf[rg * 2304 + o])
                             + Rf[(4 + rg) * 2304 + o])
                             + Rf[(8 + rg) * 2304 + o];
            }

        // ---- epilogue: logits -> BCE * mask -> per-wave sum -> atomic ----
        float lsum = 0.0f;
#pragma unroll
        for (int t = 0; t < 9; ++t) {
            const int col = t * 16 + lr;
            if (col < NVALID) {
                const float rbv = rowBias[b * NPAD + col];
#pragma unroll
                for (int i = 0; i < 4; ++i) {
                    const int row = gm0 + rg * 16 + q * 4 + i;
                    const float l = acc[t][i] + rbv;
                    float tgt;
                    if (col < 64)        tgt = oh[(size_t)row * R_ + col];
                    else if (col < 128)  tgt = ot[(size_t)row * R_ + (col - 64)];
                    else if (col == 128) tgt = ash[row];
                    else                 tgt = ast[row];
                    const float mk = masks[row];
                    const float bce = fmaxf(l, 0.0f) - l * tgt + log1pf(__expf(-fabsf(l)));
                    lsum += bce * mk;
                }
            }
        }
        for (int o = 32; o > 0; o >>= 1) lsum += __shfl_down(lsum, o, 64);
        if (lane == 0) {
            atomicAdd(&accum[0], lsum);          // one atomic per kq0-wave
            __threadfence();
            const unsigned int prev = atomicAdd((unsigned int*)(accum + 2), 1u);
            if (prev == 4u * gridDim.x - 1u) {   // last wave finalizes
                const float s = atomicAdd(&accum[0], 0.0f);
                const float m = atomicAdd(&accum[1], 0.0f);
                out[0] = s / m;
            }
        }
    }
}

extern "C" void kernel_launch(void* const* d_in, const int* in_sizes, int n_in,
                              void* d_out, int out_size, void* d_ws, size_t ws_size,
                              hipStream_t stream) {
    const float* ctx   = (const float*)d_in[0];
    const float* masks = (const float*)d_in[1];
    const float* ash   = (const float*)d_in[2];
    const float* ast   = (const float*)d_in[3];
    const float* sh    = (const float*)d_in[4];
    const float* st    = (const float*)d_in[5];
    const float* oh    = (const float*)d_in[6];
    const float* ot    = (const float*)d_in[7];
    const float* Ws_h  = (const float*)d_in[8];
    const float* bs_h  = (const float*)d_in[9];
    const float* Ws_t  = (const float*)d_in[10];
    const float* bs_t  = (const float*)d_in[11];
    const float* Wo_h  = (const float*)d_in[12];
    const float* bo_h  = (const float*)d_in[13];
    const float* Wo_t  = (const float*)d_in[14];
    const float* bo_t  = (const float*)d_in[15];
    float* out = (float*)d_out;

    char* ws = (char*)d_ws;
    float* accum   = (float*)(ws + 0);                 // [0]=loss, [1]=msum, [2]=counter
    float* rowBias = (float*)(ws + 256);               // [32][160] fp32
    unsigned short* WtG = (unsigned short*)(ws + 256 + 32 * NPAD * 4); // [160][1024] bf16

    hipMemsetAsync(accum, 0, 12, stream);
    aux_kernel<<<TBLK + B_, 256, 0, stream>>>(ctx, sh, st, masks, Wo_h, Wo_t,
                                              Ws_h, Ws_t, bo_h, bo_t, bs_h, bs_t,
                                              WtG, rowBias, accum);
    main_kernel<<<M_ / MT, NTHR, 0, stream>>>(ctx, WtG, rowBias, masks,
                                              ash, ast, oh, ot, accum, out);
}

// Round 11
// 173.935 us; speedup vs baseline: 1.1355x; 1.0274x over previous
//
#include <hip/hip_runtime.h>

// CASREL loss, B=32,S=512,H=1024,R=64 -> scalar fp32 loss.
// v12 = v9 (verified, absmax 0) + ONE change: twin-block XCD co-location.
// v9's col-split duplicated A HBM traffic (FETCH 38->72MB) because twins
// (same rows, different col-half) were consecutive bids -> round-robin onto
// DIFFERENT XCDs (no shared L2; L3 flushed each iter by harness fills).
// Remap mb = bid & 127, cg = bid >> 7: twins are bid/bid+128, and 128%8==0
// -> same XCD -> second A read hits the shared 4MB L2.
// Everything else byte-identical to v9: block = 128 rows x 80 cols, B-slice
// 160KB LDS staged once, barrier-free 32-k-step A stream, per-block reduce.

#define B_  32
#define S_  512
#define H_  1024
#define R_  64
#define M_  (B_ * S_)      // 16384 rows
#define NPAD 160           // 130 valid cols padded
#define NVALID 130
#define MT 128             // rows per block
#define CGC 80             // cols per block (2 col-groups)
#define TBLK 20            // transpose blocks (5 n-tiles x 4 k-tiles)
#define NTHR 512           // 8 waves
#define NKS (H_ / 32)      // 32 k-steps

typedef __attribute__((ext_vector_type(4))) float  floatx4;
typedef __attribute__((ext_vector_type(8))) short  short8;     // 8 bf16
typedef __attribute__((ext_vector_type(8))) unsigned short u16x8;

__device__ __forceinline__ unsigned short f2bf(float f) {
    unsigned int u = __float_as_uint(f);
    u = (u + 0x7FFFu + ((u >> 16) & 1u)) >> 16;   // RNE
    return (unsigned short)u;
}

__device__ __forceinline__ short8 cvt8(float4 a, float4 b) {
    union { unsigned short us[8]; short8 s8; } u;
    u.us[0] = f2bf(a.x); u.us[1] = f2bf(a.y); u.us[2] = f2bf(a.z); u.us[3] = f2bf(a.w);
    u.us[4] = f2bf(b.x); u.us[5] = f2bf(b.y); u.us[6] = f2bf(b.z); u.us[7] = f2bf(b.w);
    return u.s8;
}

__device__ __forceinline__ void gload16(const void* g, void* l) {
    __builtin_amdgcn_global_load_lds(
        (const __attribute__((address_space(1))) unsigned int*)g,
        (__attribute__((address_space(3))) unsigned int*)l, 16, 0, 0);
}

// ---- K1 (merged): blocks [0,TBLK) transpose WtG; blocks [TBLK,TBLK+B_) subj ----
__global__ __launch_bounds__(256) void aux_kernel(
        const float* __restrict__ ctx, const float* __restrict__ head,
        const float* __restrict__ tail, const float* __restrict__ masks,
        const float* __restrict__ Wo_h, const float* __restrict__ Wo_t,
        const float* __restrict__ Ws_h, const float* __restrict__ Ws_t,
        const float* __restrict__ bo_h, const float* __restrict__ bo_t,
        const float* __restrict__ bs_h, const float* __restrict__ bs_t,
        unsigned short* __restrict__ WtG, float* __restrict__ rowBias,
        float* __restrict__ accum) {
    const int tid = threadIdx.x;
    __shared__ float tr[32][257];      // transpose tile (pad 257: conflict-free)
    __shared__ float subj[H_];
    __shared__ float partS[4][256];
    __shared__ int cnt;
    __shared__ int   sidx[8];
    __shared__ float sw[8];

    if (blockIdx.x < TBLK) {
        const int kt = blockIdx.x / 5, nt = blockIdx.x % 5;
        const int k0 = kt * 256, n0 = nt * 32;
        if (n0 < 128) {
            const float* src = (n0 < 64) ? Wo_h : Wo_t;
            const int cb = n0 & 63;
            const int nn = tid & 31, kk = tid >> 5;   // 8 k-rows per pass
#pragma unroll
            for (int i = 0; i < 32; ++i) {
                const int k = k0 + i * 8 + kk;
                tr[nn][i * 8 + kk] = src[(size_t)k * R_ + cb + nn];
            }
            __syncthreads();
#pragma unroll
            for (int p = 0; p < 4; ++p) {
                const int chunk = p * 256 + tid;
                const int n = chunk >> 5;             // 0..31
                const int kc = (chunk & 31) * 8;
                u16x8 v;
#pragma unroll
                for (int j = 0; j < 8; ++j) v[j] = f2bf(tr[n][kc + j]);
                *(u16x8*)(WtG + (size_t)(n0 + n) * H_ + k0 + kc) = v;
            }
        } else {
#pragma unroll
            for (int p = 0; p < 4; ++p) {
                const int chunk = p * 256 + tid;
                const int n = 128 + (chunk >> 5);
                const int kc = (chunk & 31) * 8;
                u16x8 v;
#pragma unroll
                for (int j = 0; j < 8; ++j) {
                    float f = (n == 128) ? Ws_h[k0 + kc + j]
                            : (n == 129) ? Ws_t[k0 + kc + j] : 0.0f;
                    v[j] = f2bf(f);
                }
                *(u16x8*)(WtG + (size_t)n * H_ + k0 + kc) = v;
            }
        }
        return;
    }

    const int b = blockIdx.x - TBLK;
    if (tid == 0) cnt = 0;
    __syncthreads();
    float msk = 0.0f;
    for (int s = tid; s < S_; s += 256) {
        float w = 0.5f * (head[b * S_ + s] + tail[b * S_ + s]);
        if (w != 0.0f) {
            int i = atomicAdd(&cnt, 1);
            if (i < 8) { sidx[i] = s; sw[i] = w; }
        }
        msk += masks[b * S_ + s];
    }
    for (int o = 32; o > 0; o >>= 1) msk += __shfl_down(msk, o, 64);
    if ((tid & 63) == 0) atomicAdd(&accum[1], msk);
    __syncthreads();
    const int nnz = cnt < 8 ? cnt : 8;
    for (int h = tid; h < H_; h += 256) {
        float a = 0.0f;
        for (int i = 0; i < nnz; i++)
            a += sw[i] * ctx[((size_t)b * S_ + sidx[i]) * H_ + h];
        subj[h] = a;
    }
    __syncthreads();
    {   // rowBias dot: thread = (c-group of 4, k-slice of 128); float4 W loads
        const int cg = tid & 31;
        const int ks = tid >> 5;
        const int c4 = cg * 4;
        const float* W = (c4 < 64) ? Wo_h : Wo_t;
        const int cc = c4 & 63;
        const int kk0 = ks * 128;
        float ax = 0.f, ay = 0.f, az = 0.f, aw2 = 0.f;
#pragma unroll 4
        for (int k = kk0; k < kk0 + 128; ++k) {
            const float4 w = *(const float4*)(W + (size_t)k * R_ + cc);
            const float sv = subj[k];
            ax += sv * w.x; ay += sv * w.y; az += sv * w.z; aw2 += sv * w.w;
        }
        partS[0][tid] = ax; partS[1][tid] = ay;
        partS[2][tid] = az; partS[3][tid] = aw2;
    }
    __syncthreads();
    if (tid < NPAD) {
        float bias = tid < 64  ? bo_h[tid]
                   : tid < 128 ? bo_t[tid - 64]
                   : tid == 128 ? bs_h[0]
                   : tid == 129 ? bs_t[0] : 0.0f;
        float a2 = 0.0f;
        if (tid < 128) {
            const int g = tid >> 2, j = tid & 3;
#pragma unroll
            for (int s = 0; s < 8; ++s) a2 += partS[j][s * 32 + g];
        }
        rowBias[b * NPAD + tid] = bias + a2;
    }
}

// ---- K2: col-split, barrier-free streaming GEMM + BCE + reduce + finalize ----
__global__ __launch_bounds__(NTHR) void main_kernel(
        const float* __restrict__ ctx, const unsigned short* __restrict__ WtG,
        const float* __restrict__ rowBias, const float* __restrict__ masks,
        const float* __restrict__ ash, const float* __restrict__ ast,
        const float* __restrict__ oh, const float* __restrict__ ot,
        float* __restrict__ accum, float* __restrict__ accumB,
        float* __restrict__ out) {
    __shared__ __align__(16) unsigned short Bsm[CGC * H_];   // 163840 B = full LDS

    const int tid  = threadIdx.x;
    const int bid  = blockIdx.x;
    const int mb   = bid & 127, cg = bid >> 7;   // twins = bid, bid+128:
    const int gm0  = mb * MT;                    // 128%8==0 -> SAME XCD -> L2 share
    const int b    = gm0 >> 9;
    const int wave = tid >> 6, lane = tid & 63;
    const int lr = lane & 15, q = lane >> 4;     // q in 0..3
    const int col0 = cg * CGC;

    // ---- stage B once: 160KB, linear LDS dest, XOR-swizzled global source ----
#pragma unroll
    for (int p = 0; p < (CGC * H_ * 2 / 16) / NTHR; ++p) {   // 20 passes
        const int i = p * NTHR + tid;            // 16B chunk index
        const int row = i >> 7;                  // local col 0..79
        const int bytecol = (i & 127) << 4;      // 0..2032
        const int srcb = bytecol ^ ((row & 7) << 4);
        gload16((const char*)(WtG + (size_t)(col0 + row) * H_) + srcb,
                (char*)Bsm + i * 16);
    }
    __syncthreads();   // one-time drain: B resident for the whole kernel

    // ---- barrier-free K-stream ----
    const int arow = gm0 + wave * 16 + lr;       // each wave owns 16 rows
    const float* aP = ctx + (size_t)arow * H_ + q * 8;
    const int swz = (lr & 7) << 4;
    const int oe = (q << 4) ^ swz;               // kk even byte offset in 128B
    const int oo = (64 | (q << 4)) ^ swz;        // kk odd
    int rb5[5];
#pragma unroll
    for (int t = 0; t < 5; ++t) rb5[t] = (t * 16 + lr) * 2048;

    floatx4 acc[5];
#pragma unroll
    for (int t = 0; t < 5; ++t) acc[t] = (floatx4){0.f, 0.f, 0.f, 0.f};

#pragma unroll
    for (int kk = 0; kk < NKS; ++kk) {
        const float4 f0 = *(const float4*)(aP + kk * 32);
        const float4 f1 = *(const float4*)(aP + kk * 32 + 4);
        const short8 afr = cvt8(f0, f1);
        const int kb = (kk >> 1) * 128 + ((kk & 1) ? oo : oe);
#pragma unroll
        for (int t = 0; t < 5; ++t) {
            const short8 bfr = *(const short8*)((const char*)Bsm + rb5[t] + kb);
            acc[t] = __builtin_amdgcn_mfma_f32_16x16x32_bf16(afr, bfr, acc[t], 0, 0, 0);
        }
    }

    // ---- epilogue: logits -> BCE * mask -> sum ----
    float lsum = 0.0f;
#pragma unroll
    for (int t = 0; t < 5; ++t) {
        const int col = col0 + t * 16 + lr;
        if (col < NVALID) {
            const float rbv = rowBias[b * NPAD + col];
#pragma unroll
            for (int i = 0; i < 4; ++i) {
                const int row = gm0 + wave * 16 + q * 4 + i;
                const float l = acc[t][i] + rbv;
                float tgt;
                if (col < 64)        tgt = oh[(size_t)row * R_ + col];
                else if (col < 128)  tgt = ot[(size_t)row * R_ + (col - 64)];
                else if (col == 128) tgt = ash[row];
                else                 tgt = ast[row];
                const float mk = masks[row];
                const float bce = fmaxf(l, 0.0f) - l * tgt + log1pf(__expf(-fabsf(l)));
                lsum += bce * mk;
            }
        }
    }
    for (int o = 32; o > 0; o >>= 1) lsum += __shfl_down(lsum, o, 64);
    if (lane == 0) atomicAdd(&accumB[bid], lsum);   // per-block slot (no LDS left)
    __syncthreads();   // all 8 wave-atomics complete before read
    if (tid == 0) {
        const float s0 = atomicAdd(&accumB[bid], 0.0f);   // read-back (returns old)
        atomicAdd(&accum[0], s0);
        __threadfence();
        const unsigned int prev = atomicAdd((unsigned int*)(accum + 2), 1u);
        if (prev == gridDim.x - 1) {   // last block finalizes
            const float s = atomicAdd(&accum[0], 0.0f);
            const float m = atomicAdd(&accum[1], 0.0f);
            out[0] = s / m;
        }
    }
}

extern "C" void kernel_launch(void* const* d_in, const int* in_sizes, int n_in,
                              void* d_out, int out_size, void* d_ws, size_t ws_size,
                              hipStream_t stream) {
    const float* ctx   = (const float*)d_in[0];
    const float* masks = (const float*)d_in[1];
    const float* ash   = (const float*)d_in[2];
    const float* ast   = (const float*)d_in[3];
    const float* sh    = (const float*)d_in[4];
    const float* st    = (const float*)d_in[5];
    const float* oh    = (const float*)d_in[6];
    const float* ot    = (const float*)d_in[7];
    const float* Ws_h  = (const float*)d_in[8];
    const float* bs_h  = (const float*)d_in[9];
    const float* Ws_t  = (const float*)d_in[10];
    const float* bs_t  = (const float*)d_in[11];
    const float* Wo_h  = (const float*)d_in[12];
    const float* bo_h  = (const float*)d_in[13];
    const float* Wo_t  = (const float*)d_in[14];
    const float* bo_t  = (const float*)d_in[15];
    float* out = (float*)d_out;

    char* ws = (char*)d_ws;
    float* accum   = (float*)(ws + 0);        // [0]=loss, [1]=msum, [2]=counter
    float* accumB  = (float*)(ws + 256);      // [256] per-block partials
    float* rowBias = (float*)(ws + 2048);     // [32][160] fp32
    unsigned short* WtG = (unsigned short*)(ws + 2048 + 32 * NPAD * 4); // [160][1024] bf16

    hipMemsetAsync(ws, 0, 1280, stream);      // accum + accumB
    aux_kernel<<<TBLK + B_, 256, 0, stream>>>(ctx, sh, st, masks, Wo_h, Wo_t,
                                              Ws_h, Ws_t, bo_h, bo_t, bs_h, bs_t,
                                              WtG, rowBias, accum);
    main_kernel<<<(M_ / MT) * 2, NTHR, 0, stream>>>(ctx, WtG, rowBias, masks,
                                                    ash, ast, oh, ot,
                                                    accum, accumB, out);
}

// Round 12
// 161.370 us; speedup vs baseline: 1.2239x; 1.0779x over previous
//
#include <hip/hip_runtime.h>

// CASREL loss, B=32,S=512,H=1024,R=64 -> scalar fp32 loss.
// v13 == v8 (best verified: 162.1us total, main 41.5us, absmax 0.0).
// Final session conclusions (12 structural variants, all counter-verified):
//  - Designs reading each ctx byte once from disjoint per-CU rows converge
//    at ~1.5 TB/s A-ingestion (v1/v8); this is the concurrency ceiling for
//    8-16 wave structures here, not an HBM or MFMA roofline.
//  - Occupancy (v5,v11), manual vmcnt pipelines (v6), fewer barrier rounds
//    (v7,v10) are all null-to-negative. Staged-bytes/CU is the only lever
//    that moved main (v8: MT=64 halves B re-reads -> 48.7->41.5us).
//  - Col-split streams (v9) trade 2x A traffic for rate (55us); XCD-pair
//    dedup (v12) removes the traffic but halves the fetch concurrency
//    (81us). The product never beats v8.
//  - ~125us/iter is harness workspace-poison fill (3x256MB @ 6.5TB/s),
//    a fixed floor that also flushes L3 between iterations.

#define B_  32
#define S_  512
#define H_  1024
#define R_  64
#define M_  (B_ * S_)      // 16384 rows
#define NPAD 160           // 130 valid cols padded
#define NVALID 130
#define BK 128
#define BKP 136            // A LDS pad (shorts)
#define MT 64              // rows per block
#define NCHUNK (H_ / BK)   // 8
#define TBLK 20            // transpose blocks (5 n-tiles x 4 k-tiles)
#define NTHR 512           // 8 waves

typedef __attribute__((ext_vector_type(4))) float  floatx4;
typedef __attribute__((ext_vector_type(8))) short  short8;     // 8 bf16
typedef __attribute__((ext_vector_type(4))) unsigned short u16x4;
typedef __attribute__((ext_vector_type(8))) unsigned short u16x8;

__device__ __forceinline__ unsigned short f2bf(float f) {
    unsigned int u = __float_as_uint(f);
    u = (u + 0x7FFFu + ((u >> 16) & 1u)) >> 16;   // RNE
    return (unsigned short)u;
}

__device__ __forceinline__ u16x8 cvt8u(float4 a, float4 b) {
    u16x8 u;
    u[0] = f2bf(a.x); u[1] = f2bf(a.y); u[2] = f2bf(a.z); u[3] = f2bf(a.w);
    u[4] = f2bf(b.x); u[5] = f2bf(b.y); u[6] = f2bf(b.z); u[7] = f2bf(b.w);
    return u;
}

// ---- K1 (merged): blocks [0,TBLK) transpose WtG; blocks [TBLK,TBLK+B_) subj ----
__global__ __launch_bounds__(256) void aux_kernel(
        const float* __restrict__ ctx, const float* __restrict__ head,
        const float* __restrict__ tail, const float* __restrict__ masks,
        const float* __restrict__ Wo_h, const float* __restrict__ Wo_t,
        const float* __restrict__ Ws_h, const float* __restrict__ Ws_t,
        const float* __restrict__ bo_h, const float* __restrict__ bo_t,
        const float* __restrict__ bs_h, const float* __restrict__ bs_t,
        unsigned short* __restrict__ WtG, float* __restrict__ rowBias,
        float* __restrict__ accum) {
    const int tid = threadIdx.x;
    __shared__ float tr[32][257];      // transpose tile (pad 257: conflict-free)
    __shared__ float subj[H_];
    __shared__ float partS[4][256];
    __shared__ int cnt;
    __shared__ int   sidx[8];
    __shared__ float sw[8];

    if (blockIdx.x < TBLK) {
        const int kt = blockIdx.x / 5, nt = blockIdx.x % 5;
        const int k0 = kt * 256, n0 = nt * 32;
        if (n0 < 128) {
            const float* src = (n0 < 64) ? Wo_h : Wo_t;
            const int cb = n0 & 63;
            const int nn = tid & 31, kk = tid >> 5;   // 8 k-rows per pass
#pragma unroll
            for (int i = 0; i < 32; ++i) {
                const int k = k0 + i * 8 + kk;
                tr[nn][i * 8 + kk] = src[(size_t)k * R_ + cb + nn];
            }
            __syncthreads();
#pragma unroll
            for (int p = 0; p < 4; ++p) {
                const int chunk = p * 256 + tid;
                const int n = chunk >> 5;             // 0..31
                const int kc = (chunk & 31) * 8;
                u16x8 v;
#pragma unroll
                for (int j = 0; j < 8; ++j) v[j] = f2bf(tr[n][kc + j]);
                *(u16x8*)(WtG + (size_t)(n0 + n) * H_ + k0 + kc) = v;
            }
        } else {
#pragma unroll
            for (int p = 0; p < 4; ++p) {
                const int chunk = p * 256 + tid;
                const int n = 128 + (chunk >> 5);
                const int kc = (chunk & 31) * 8;
                u16x8 v;
#pragma unroll
                for (int j = 0; j < 8; ++j) {
                    float f = (n == 128) ? Ws_h[k0 + kc + j]
                            : (n == 129) ? Ws_t[k0 + kc + j] : 0.0f;
                    v[j] = f2bf(f);
                }
                *(u16x8*)(WtG + (size_t)n * H_ + k0 + kc) = v;
            }
        }
        return;
    }

    const int b = blockIdx.x - TBLK;
    if (tid == 0) cnt = 0;
    __syncthreads();
    float msk = 0.0f;
    for (int s = tid; s < S_; s += 256) {
        float w = 0.5f * (head[b * S_ + s] + tail[b * S_ + s]);
        if (w != 0.0f) {
            int i = atomicAdd(&cnt, 1);
            if (i < 8) { sidx[i] = s; sw[i] = w; }
        }
        msk += masks[b * S_ + s];
    }
    for (int o = 32; o > 0; o >>= 1) msk += __shfl_down(msk, o, 64);
    if ((tid & 63) == 0) atomicAdd(&accum[1], msk);
    __syncthreads();
    const int nnz = cnt < 8 ? cnt : 8;
    for (int h = tid; h < H_; h += 256) {
        float a = 0.0f;
        for (int i = 0; i < nnz; i++)
            a += sw[i] * ctx[((size_t)b * S_ + sidx[i]) * H_ + h];
        subj[h] = a;
    }
    __syncthreads();
    {   // rowBias dot: thread = (c-group of 4, k-slice of 128); float4 W loads
        const int cg = tid & 31;
        const int ks = tid >> 5;
        const int c4 = cg * 4;
        const float* W = (c4 < 64) ? Wo_h : Wo_t;
        const int cc = c4 & 63;
        const int kk0 = ks * 128;
        float ax = 0.f, ay = 0.f, az = 0.f, aw2 = 0.f;
#pragma unroll 4
        for (int k = kk0; k < kk0 + 128; ++k) {
            const float4 w = *(const float4*)(W + (size_t)k * R_ + cc);
            const float sv = subj[k];
            ax += sv * w.x; ay += sv * w.y; az += sv * w.z; aw2 += sv * w.w;
        }
        partS[0][tid] = ax; partS[1][tid] = ay;
        partS[2][tid] = az; partS[3][tid] = aw2;
    }
    __syncthreads();
    if (tid < NPAD) {
        float bias = tid < 64  ? bo_h[tid]
                   : tid < 128 ? bo_t[tid - 64]
                   : tid == 128 ? bs_h[0]
                   : tid == 129 ? bs_t[0] : 0.0f;
        float a2 = 0.0f;
        if (tid < 128) {
            const int g = tid >> 2, j = tid & 3;
#pragma unroll
            for (int s = 0; s < 8; ++s) a2 += partS[j][s * 32 + g];
        }
        rowBias[b * NPAD + tid] = bias + a2;
    }
}

// ---- K2: MT=64, 8-wave, BK=128 GEMM + BCE + masked reduction + finalize ----
__global__ __launch_bounds__(NTHR, 2) void main_kernel(
        const float* __restrict__ ctx, const unsigned short* __restrict__ WtG,
        const float* __restrict__ rowBias, const float* __restrict__ masks,
        const float* __restrict__ ash, const float* __restrict__ ast,
        const float* __restrict__ oh, const float* __restrict__ ot,
        float* __restrict__ accum, float* __restrict__ out) {
    __shared__ __align__(16) unsigned short Asm[MT * BKP];   // 17.4 KB
    __shared__ __align__(16) unsigned short Bsm[NPAD * BK];  // 40 KB
    __shared__ float rbuf[8];

    const int tid  = threadIdx.x;
    const int gm0  = blockIdx.x * MT;
    const int b    = gm0 >> 9;                // 512 rows per batch (MT=64 divides)
    const int wave = tid >> 6, lane = tid & 63;
    const int wm = wave & 3;            // row group (16 rows), 0..3
    const int wn = wave >> 2;           // col half (80 cols = 5 tiles), 0..1
    const int lr = lane & 15, q = lane >> 4;   // q in 0..3

    // A staging: thread -> row ar = tid>>3 (0..63), 16 floats at col (tid&7)*16
    const int ar = tid >> 3, as_ = (tid & 7) * 16;
    const float* aSrc = ctx + (size_t)(gm0 + ar) * H_ + as_;
    unsigned short* aDst = &Asm[ar * BKP + as_];

    // B staging: rows {br, br+64, br+128(if tid<256)}, 16 shorts at (tid&7)*16
    // LDS layout: [row][128] shorts, byte col XOR-swizzled by ((row&7)<<4)
    const int br = tid >> 3, bs0 = (tid & 7) * 16;   // shorts
    const unsigned short* bSrc = WtG + (size_t)br * H_ + bs0;
    const int bswz = (br & 7) << 4;                  // rows differ by 64 -> same swz
    char* bDstB = (char*)Bsm + br * 256;             // + ((bytecol)^bswz)
    const bool bp2 = (tid < 256);                    // wave-uniform (waves 0-3)

    // compute-side fragment offsets
    const int aOff = (wm * 16 + lr) * BKP + q * 8;   // shorts
    int bOff[5];
#pragma unroll
    for (int tt = 0; tt < 5; ++tt) {
        const int row = wn * 80 + tt * 16 + lr;
        bOff[tt] = row * 256 + ((q * 16) ^ ((row & 7) << 4));   // bytes; ^(kk<<1) per substep
    }

    floatx4 acc[5];
#pragma unroll
    for (int tt = 0; tt < 5; ++tt) acc[tt] = (floatx4){0.f, 0.f, 0.f, 0.f};

    // staging registers for one chunk
    float4 aR[4];
    u16x8  bR[6];

#define LOADREGS(k0) do {                                                      \
        _Pragma("unroll")                                                      \
        for (int i = 0; i < 4; ++i)                                            \
            aR[i] = *(const float4*)(aSrc + (k0) + i * 4);                     \
        bR[0] = *(const u16x8*)(bSrc + (k0));                                  \
        bR[1] = *(const u16x8*)(bSrc + (k0) + 8);                              \
        bR[2] = *(const u16x8*)(bSrc + (size_t)64 * H_ + (k0));                \
        bR[3] = *(const u16x8*)(bSrc + (size_t)64 * H_ + (k0) + 8);            \
        if (bp2) {                                                             \
            bR[4] = *(const u16x8*)(bSrc + (size_t)128 * H_ + (k0));           \
            bR[5] = *(const u16x8*)(bSrc + (size_t)128 * H_ + (k0) + 8);       \
        }                                                                      \
    } while (0)

#define WRITE_LDS() do {                                                       \
        *(u16x8*)(aDst)     = cvt8u(aR[0], aR[1]);                             \
        *(u16x8*)(aDst + 8) = cvt8u(aR[2], aR[3]);                             \
        *(u16x8*)(bDstB + ((bs0 * 2)      ^ bswz)) = bR[0];                    \
        *(u16x8*)(bDstB + ((bs0 * 2 + 16) ^ bswz)) = bR[1];                    \
        *(u16x8*)(bDstB + 64 * 256 + ((bs0 * 2)      ^ bswz)) = bR[2];         \
        *(u16x8*)(bDstB + 64 * 256 + ((bs0 * 2 + 16) ^ bswz)) = bR[3];         \
        if (bp2) {                                                             \
            *(u16x8*)(bDstB + 128 * 256 + ((bs0 * 2)      ^ bswz)) = bR[4];    \
            *(u16x8*)(bDstB + 128 * 256 + ((bs0 * 2 + 16) ^ bswz)) = bR[5];    \
        }                                                                      \
    } while (0)

    LOADREGS(0);
    for (int t = 0; t < NCHUNK; ++t) {
        __syncthreads();                 // (a) prior chunk's LDS reads done
        WRITE_LDS();
        if (t < NCHUNK - 1) LOADREGS((t + 1) * BK);   // issue next loads now
        __syncthreads();                 // (b) LDS writes visible
        // compute chunk t (loads for t+1 in flight under this)
#pragma unroll
        for (int kk = 0; kk < BK; kk += 32) {
            short8 afr = *(const short8*)&Asm[aOff + kk];
#pragma unroll
            for (int tt = 0; tt < 5; ++tt) {
                short8 bfr = *(const short8*)((const char*)Bsm + (bOff[tt] ^ (kk << 1)));
                acc[tt] = __builtin_amdgcn_mfma_f32_16x16x32_bf16(afr, bfr, acc[tt], 0, 0, 0);
            }
        }
    }
#undef LOADREGS
#undef WRITE_LDS

    // epilogue: logits -> BCE * mask -> sum
    float lsum = 0.0f;
#pragma unroll
    for (int tt = 0; tt < 5; ++tt) {
        const int col = wn * 80 + tt * 16 + lr;
        if (col < NVALID) {
            const float rb = rowBias[b * NPAD + col];
#pragma unroll
            for (int i = 0; i < 4; ++i) {
                const int row = gm0 + wm * 16 + q * 4 + i;
                const float l = acc[tt][i] + rb;
                float tgt;
                if (col < 64)        tgt = oh[(size_t)row * R_ + col];
                else if (col < 128)  tgt = ot[(size_t)row * R_ + (col - 64)];
                else if (col == 128) tgt = ash[row];
                else                 tgt = ast[row];
                const float mk = masks[row];
                const float bce = fmaxf(l, 0.0f) - l * tgt + log1pf(__expf(-fabsf(l)));
                lsum += bce * mk;
            }
        }
    }
    for (int o = 32; o > 0; o >>= 1) lsum += __shfl_down(lsum, o, 64);
    if (lane == 0) rbuf[wave] = lsum;
    __syncthreads();
    if (tid == 0) {
        float s0 = 0.0f;
#pragma unroll
        for (int w = 0; w < 8; ++w) s0 += rbuf[w];
        atomicAdd(&accum[0], s0);
        __threadfence();
        const unsigned int prev = atomicAdd((unsigned int*)(accum + 2), 1u);
        if (prev == gridDim.x - 1) {   // last block finalizes
            const float s = atomicAdd(&accum[0], 0.0f);
            const float m = atomicAdd(&accum[1], 0.0f);
            out[0] = s / m;
        }
    }
}

extern "C" void kernel_launch(void* const* d_in, const int* in_sizes, int n_in,
                              void* d_out, int out_size, void* d_ws, size_t ws_size,
                              hipStream_t stream) {
    const float* ctx   = (const float*)d_in[0];
    const float* masks = (const float*)d_in[1];
    const float* ash   = (const float*)d_in[2];
    const float* ast   = (const float*)d_in[3];
    const float* sh    = (const float*)d_in[4];
    const float* st    = (const float*)d_in[5];
    const float* oh    = (const float*)d_in[6];
    const float* ot    = (const float*)d_in[7];
    const float* Ws_h  = (const float*)d_in[8];
    const float* bs_h  = (const float*)d_in[9];
    const float* Ws_t  = (const float*)d_in[10];
    const float* bs_t  = (const float*)d_in[11];
    const float* Wo_h  = (const float*)d_in[12];
    const float* bo_h  = (const float*)d_in[13];
    const float* Wo_t  = (const float*)d_in[14];
    const float* bo_t  = (const float*)d_in[15];
    float* out = (float*)d_out;

    char* ws = (char*)d_ws;
    float* accum   = (float*)(ws + 0);                 // [0]=loss, [1]=msum, [2]=counter
    float* rowBias = (float*)(ws + 256);               // [32][160] fp32
    unsigned short* WtG = (unsigned short*)(ws + 256 + 32 * NPAD * 4); // [160][1024] bf16

    hipMemsetAsync(accum, 0, 12, stream);
    aux_kernel<<<TBLK + B_, 256, 0, stream>>>(ctx, sh, st, masks, Wo_h, Wo_t,
                                              Ws_h, Ws_t, bo_h, bo_t, bs_h, bs_t,
                                              WtG, rowBias, accum);
    main_kernel<<<M_ / MT, NTHR, 0, stream>>>(ctx, WtG, rowBias, masks,
                                              ash, ast, oh, ot, accum, out);
}